// Round 2
// baseline (377.050 us; speedup 1.0000x reference)
//
#include <hip/hip_runtime.h>

// GCN layer: support = X@W ; out = relu(scatter(vals * support[cols]) + bias)
// N_NODES=65536, N_EDGES=1048576, IN_F=OUT_F=64, fp32 in/out.
//
// Ledger: R2 CSR -> R5 bucket sort -> R7 MFMA bf16 GEMM (152) -> R8 fused CSR
// build (144) -> R11 concurrent gemm+scatter mega (143) -> R12 fixed-capacity
// 512-bucket staging + reg-cached LDS sort (52.3) -> R13 per-row global-atomic
// scatter FAILED (120.3: 1M atomic-with-return chains, serialized @36 VGPR,
// 8B scatter sector amplification 75MB writes; every pipe <2% busy).
// R14: revert scatter to R12 (LDS-aggregated cursors, contiguous 64B runs);
//      gather drops the phase-A sort entirely: 32KB LDS fp32 accumulator per
//      bucket, edges consumed UNSORTED via wave-uniform s_load; per edge =
//      1 ushort VMEM (S row) + v_mul + 1 ds_add_f32 (lane=feature, conflict-
//      free). Deletes hist/scan/sort (~3 LDS ops/edge + 14 barriers -> 2).

#define NF    64
#define NBKT  512      // dst-row buckets; 128 rows each (shift=7)
#define RPB   128      // rows per bucket
#define BCAP  3072     // fixed slots per bucket (mean 2048, +22 sigma)
#define CHUNK 4096     // edges per scatter chunk (256 thr x 16)

typedef __attribute__((ext_vector_type(8))) short bf16x8;
typedef __attribute__((ext_vector_type(4))) float floatx4;

__device__ __forceinline__ unsigned short f2bf(float f) {
    unsigned u = __float_as_uint(f);
    return (unsigned short)((u + 0x7FFFu + ((u >> 16) & 1u)) >> 16);   // RNE
}
__device__ __forceinline__ float bf2f(unsigned short h) {
    return __uint_as_float(((unsigned)h) << 16);
}

// ---------------------------------------------------------------------------
// Kernel 1 (MEGA): GEMM tiles and scatter chunks co-resident in one grid.
// 1280 blocks x 256 thr: b%5==4 -> scatter chunk b/5 (256 chunks x 4096
// edges); else gemm tile (b/5)*4+(b%5) (1024 tiles). Scatter writes into
// FIXED bucket regions staged[bkt*BCAP ...] via global cursor reservation
// (one atomic per bucket per chunk, LDS-aggregated); contiguous 64B runs.
// ---------------------------------------------------------------------------
__global__ __launch_bounds__(256) void gemm_scatter(
    const float* __restrict__ X, const float* __restrict__ W,
    unsigned short* __restrict__ S16,
    const int* __restrict__ rows, const int* __restrict__ cols,
    const float* __restrict__ vals, int* __restrict__ bucket_cursor,
    int2* __restrict__ staged, int n_edges, int shift)
{
    __shared__ short xs[64 * 72];   // gemm: X tile [row][k] (2-way alias: free)
    __shared__ short wt[64 * 72];   // gemm: W^T    [n][k]
    __shared__ int   hist[NBKT];    // scatter
    __shared__ int   cur[NBKT];     // scatter (global write index per bucket)

    const int tid = threadIdx.x;
    const int b   = blockIdx.x;

    if (b % 5 != 4) {
        // ---------------- GEMM tile ----------------
        const int tile = (b / 5) * 4 + (b % 5);
        const int row0 = tile * 64;
        {
            const float4* W4 = (const float4*)W;
            #pragma unroll
            for (int it = 0; it < 4; ++it) {
                int idx = tid + 256 * it;
                int k = idx >> 4, n4 = idx & 15;
                float4 w = W4[idx];
                wt[(n4 * 4 + 0) * 72 + k] = f2bf(w.x);
                wt[(n4 * 4 + 1) * 72 + k] = f2bf(w.y);
                wt[(n4 * 4 + 2) * 72 + k] = f2bf(w.z);
                wt[(n4 * 4 + 3) * 72 + k] = f2bf(w.w);
            }
        }
        {
            const float4* X4 = (const float4*)X + (size_t)row0 * 16;
            #pragma unroll
            for (int it = 0; it < 4; ++it) {
                int idx = tid + 256 * it;
                int r = idx >> 4, c4 = idx & 15;
                float4 v = X4[idx];
                short4 s = { (short)f2bf(v.x), (short)f2bf(v.y),
                             (short)f2bf(v.z), (short)f2bf(v.w) };
                *(short4*)&xs[r * 72 + c4 * 4] = s;
            }
        }
        __syncthreads();

        const int w    = tid >> 6;
        const int lane = tid & 63;
        const int m    = lane & 15;
        const int q    = lane >> 4;

        const int a_off = (16 * w + m) * 72 + q * 8;
        const bf16x8 A0 = *(const bf16x8*)&xs[a_off];
        const bf16x8 A1 = *(const bf16x8*)&xs[a_off + 32];

        floatx4 acc[4];
        #pragma unroll
        for (int t = 0; t < 4; ++t) {
            const int b_off = (16 * t + m) * 72 + q * 8;
            const bf16x8 B0 = *(const bf16x8*)&wt[b_off];
            const bf16x8 B1 = *(const bf16x8*)&wt[b_off + 32];
            floatx4 c = {0.f, 0.f, 0.f, 0.f};
            c = __builtin_amdgcn_mfma_f32_16x16x32_bf16(A0, B0, c, 0, 0, 0);
            c = __builtin_amdgcn_mfma_f32_16x16x32_bf16(A1, B1, c, 0, 0, 0);
            acc[t] = c;
        }
        #pragma unroll
        for (int t = 0; t < 4; ++t)
            #pragma unroll
            for (int r = 0; r < 4; ++r)
                S16[(size_t)(row0 + 16 * w + q * 4 + r) * NF + 16 * t + m] =
                    f2bf(acc[t][r]);
    } else {
        // ---------------- scatter chunk ----------------
        const int chunk = b / 5;
        for (int i = tid; i < NBKT; i += 256) hist[i] = 0;
        __syncthreads();
        const int base = chunk * CHUNK;
        const int lim  = min(CHUNK, n_edges - base);

        if (lim == CHUNK) {
            const int4*   R4 = (const int4*)(rows + base);
            const int4*   C4 = (const int4*)(cols + base);
            const float4* V4 = (const float4*)(vals + base);
            int4 r0 = R4[tid], r1 = R4[tid + 256];
            int4 r2 = R4[tid + 512], r3 = R4[tid + 768];
            #define HINC(rr) atomicAdd(&hist[((unsigned)(rr)) >> shift], 1)
            HINC(r0.x); HINC(r0.y); HINC(r0.z); HINC(r0.w);
            HINC(r1.x); HINC(r1.y); HINC(r1.z); HINC(r1.w);
            HINC(r2.x); HINC(r2.y); HINC(r2.z); HINC(r2.w);
            HINC(r3.x); HINC(r3.y); HINC(r3.z); HINC(r3.w);
            #undef HINC
            __syncthreads();
            for (int i = tid; i < NBKT; i += 256) {
                int h = hist[i];
                cur[i] = h ? (i * BCAP + atomicAdd(&bucket_cursor[i], h)) : 0;
            }
            __syncthreads();
            int4 c0 = C4[tid], c1 = C4[tid + 256];
            int4 c2 = C4[tid + 512], c3 = C4[tid + 768];
            float4 v0 = V4[tid], v1 = V4[tid + 256];
            float4 v2 = V4[tid + 512], v3 = V4[tid + 768];
            #define PUT(rr, cc, vv) { \
                int bkt = ((unsigned)(rr)) >> shift; \
                int p = atomicAdd(&cur[bkt], 1); \
                if (p - bkt * BCAP < BCAP) \
                    staged[p] = make_int2((int)(((unsigned)(rr) << 16) | (unsigned)(cc)), \
                                          __float_as_int(vv)); }
            PUT(r0.x, c0.x, v0.x); PUT(r0.y, c0.y, v0.y);
            PUT(r0.z, c0.z, v0.z); PUT(r0.w, c0.w, v0.w);
            PUT(r1.x, c1.x, v1.x); PUT(r1.y, c1.y, v1.y);
            PUT(r1.z, c1.z, v1.z); PUT(r1.w, c1.w, v1.w);
            PUT(r2.x, c2.x, v2.x); PUT(r2.y, c2.y, v2.y);
            PUT(r2.z, c2.z, v2.z); PUT(r2.w, c2.w, v2.w);
            PUT(r3.x, c3.x, v3.x); PUT(r3.y, c3.y, v3.y);
            PUT(r3.z, c3.z, v3.z); PUT(r3.w, c3.w, v3.w);
            #undef PUT
        } else {
            for (int i = tid; i < lim; i += 256)
                atomicAdd(&hist[((unsigned)rows[base + i]) >> shift], 1);
            __syncthreads();
            for (int i = tid; i < NBKT; i += 256) {
                int h = hist[i];
                cur[i] = h ? (i * BCAP + atomicAdd(&bucket_cursor[i], h)) : 0;
            }
            __syncthreads();
            for (int i = tid; i < lim; i += 256) {
                int r = rows[base + i];
                int bkt = ((unsigned)r) >> shift;
                int p = atomicAdd(&cur[bkt], 1);
                if (p - bkt * BCAP < BCAP)
                    staged[p] = make_int2((int)(((unsigned)r << 16) | (unsigned)cols[base + i]),
                                          __float_as_int(vals[base + i]));
            }
        }
    }
}

// ---------------------------------------------------------------------------
// Kernel 2: NO-SORT bucket accumulate. One block (512 thr, 8 waves) per
// bucket; 32KB LDS fp32 acc[128][64]. Edges consumed unsorted: wave-uniform
// loop -> edge payload on the scalar pipe (s_load); per edge: 1 ushort VMEM
// (S row, lane=feature, 128B/wave) + v_mul + ds_add_f32 (consecutive lane
// addrs -> conflict-free). No hist, no scan, no sort; 2 barriers total.
// ---------------------------------------------------------------------------
__global__ __launch_bounds__(512) void bucket_accum(
    const int* __restrict__ bucket_cursor, const int2* __restrict__ staged,
    const unsigned short* __restrict__ S16, const float* __restrict__ bias,
    float* __restrict__ out)
{
    __shared__ float acc[RPB * NF];    // 32 KB

    const int k    = blockIdx.x;
    const int t    = threadIdx.x;
    const int w    = t >> 6;
    const int lane = t & 63;

    // zero accumulator: 512 thr x 16 floats (ds_write_b128 x4)
    #pragma unroll
    for (int i = 0; i < 4; ++i) {
        float4 z = {0.f, 0.f, 0.f, 0.f};
        *(float4*)&acc[t * 16 + i * 4] = z;
    }

    const int cnt = min(bucket_cursor[k], BCAP);
    const int2* ep = staged + (size_t)k * BCAP;

    // even split of edges across the 8 waves (rows are NOT partitioned)
    const int per = (cnt + 7) >> 3;
    const int jb  = w * per;
    const int je  = min(jb + per, cnt);

    __syncthreads();

    #define ACC(e) { \
        const unsigned rx = (unsigned)(e).x; \
        const float sv = bf2f(S16[((rx & 0xFFFFu) << 6) + (unsigned)lane]); \
        atomicAdd(&acc[(((rx >> 16) & (RPB - 1)) << 6) + lane], \
                  __int_as_float((e).y) * sv); }

    int j = jb;
    for (; j + 8 <= je; j += 8) {
        const int2 e0 = ep[j + 0];
        const int2 e1 = ep[j + 1];
        const int2 e2 = ep[j + 2];
        const int2 e3 = ep[j + 3];
        const int2 e4 = ep[j + 4];
        const int2 e5 = ep[j + 5];
        const int2 e6 = ep[j + 6];
        const int2 e7 = ep[j + 7];
        ACC(e0); ACC(e1); ACC(e2); ACC(e3);
        ACC(e4); ACC(e5); ACC(e6); ACC(e7);
    }
    for (; j < je; ++j) {
        const int2 e = ep[j];
        ACC(e);
    }
    #undef ACC

    __syncthreads();

    // epilogue: wave w writes rows 16w..16w+15; lane = feature (coalesced)
    const float bv = bias[lane];
    #pragma unroll
    for (int rr = 0; rr < 16; ++rr) {
        const int row = w * 16 + rr;
        const float v = acc[(row << 6) + lane] + bv;
        out[((size_t)(k * RPB + row) << 6) + lane] = fmaxf(v, 0.f);
    }
}

extern "C" void kernel_launch(void* const* d_in, const int* in_sizes, int n_in,
                              void* d_out, int out_size, void* d_ws, size_t ws_size,
                              hipStream_t stream)
{
    const float* X     = (const float*)d_in[0];
    const int*   erows = (const int*)  d_in[1];
    const int*   ecols = (const int*)  d_in[2];
    const float* evals = (const float*)d_in[3];
    const float* W     = (const float*)d_in[4];
    const float* bias  = (const float*)d_in[5];
    float*       out   = (float*)d_out;

    const int n_nodes = in_sizes[0] / NF;   // 65536
    const int n_edges = in_sizes[1];        // 1048576
    int shift = 0; while ((NBKT << shift) < n_nodes) ++shift;   // 7

    // workspace layout
    char* ws = (char*)d_ws;
    unsigned short* S16 = (unsigned short*)(ws);                          // 8 MB
    int2* staged        = (int2*)(ws + (size_t)n_nodes * NF * 2);         // 12.6 MB
    int*  bucket_cursor = (int*)((char*)staged + (size_t)NBKT * BCAP * 8);// 2 KB

    const int gemm_tiles = n_nodes / 64;                 // 1024
    const int schunks    = (n_edges + CHUNK - 1) / CHUNK;// 256
    const int mega       = gemm_tiles + schunks;         // 1280 (4:1 interleave)

    hipMemsetAsync(bucket_cursor, 0, (size_t)NBKT * 4, stream);
    gemm_scatter<<<mega, 256, 0, stream>>>(X, W, S16, erows, ecols, evals,
                                           bucket_cursor, staged, n_edges, shift);
    bucket_accum<<<NBKT, 512, 0, stream>>>(bucket_cursor, staged, S16, bias, out);
}

// Round 3
// 82.716 us; speedup vs baseline: 4.5584x; 4.5584x over previous
//
#include <hip/hip_runtime.h>

// GCN layer: support = X@W ; out = relu(scatter(vals * support[cols]) + bias)
// N_NODES=65536, N_EDGES=1048576, IN_F=OUT_F=64, fp32 in/out.
//
// Ledger: R2 CSR -> R5 bucket sort -> R7 MFMA bf16 GEMM (152) -> R8 fused CSR
// build (144) -> R11 concurrent gemm+scatter mega (143) -> R12 fixed-capacity
// 512-bucket staging + reg-cached LDS sort (52.3) -> R13 per-row global-atomic
// scatter FAILED (120.3: 1M atomic-with-return chains + 8B-scatter sector
// amplification) -> R14 no-sort LDS float-atomic accum FAILED (377: HIP
// atomicAdd(float*) on LDS under IEEE-denorm mode = ds_read/ds_cmpswap CAS
// LOOP, not ds_add_f32; VGPR=16, every pipe <4%, 354us).
// R15: same no-sort accumulate but FIXED-POINT INT32 (scale 2^14) via
//      atomicAdd(int*) -> native ds_add_u32, no return, no CAS. Bound audit:
//      |msg| <= ~6, degree <= ~55 -> |sum*2^14| <= 6.3M << 2^31; quant err
//      <= 64*2^-15 = 2e-3 << 0.0625 tolerance. 1024-thr blocks (16 waves,
//      2 blk/CU) x 8-deep unroll -> ~256 gathers in flight per CU.

#define NF    64
#define NBKT  512      // dst-row buckets; 128 rows each (shift=7)
#define RPB   128      // rows per bucket
#define BCAP  3072     // fixed slots per bucket (mean 2048, +22 sigma)
#define CHUNK 4096     // edges per scatter chunk (256 thr x 16)

#define SCALE_F   16384.0f          // 2^14 fixed-point scale
#define INV_SCALE 6.103515625e-05f  // 2^-14

typedef __attribute__((ext_vector_type(8))) short bf16x8;
typedef __attribute__((ext_vector_type(4))) float floatx4;

__device__ __forceinline__ unsigned short f2bf(float f) {
    unsigned u = __float_as_uint(f);
    return (unsigned short)((u + 0x7FFFu + ((u >> 16) & 1u)) >> 16);   // RNE
}
__device__ __forceinline__ float bf2f(unsigned short h) {
    return __uint_as_float(((unsigned)h) << 16);
}

// ---------------------------------------------------------------------------
// Kernel 1 (MEGA): GEMM tiles and scatter chunks co-resident in one grid.
// 1280 blocks x 256 thr: b%5==4 -> scatter chunk b/5 (256 chunks x 4096
// edges); else gemm tile (b/5)*4+(b%5) (1024 tiles). Scatter writes into
// FIXED bucket regions staged[bkt*BCAP ...] via global cursor reservation
// (one atomic per bucket per chunk, LDS-aggregated); contiguous 64B runs.
// [R12-proven version, unchanged]
// ---------------------------------------------------------------------------
__global__ __launch_bounds__(256) void gemm_scatter(
    const float* __restrict__ X, const float* __restrict__ W,
    unsigned short* __restrict__ S16,
    const int* __restrict__ rows, const int* __restrict__ cols,
    const float* __restrict__ vals, int* __restrict__ bucket_cursor,
    int2* __restrict__ staged, int n_edges, int shift)
{
    __shared__ short xs[64 * 72];   // gemm: X tile [row][k] (2-way alias: free)
    __shared__ short wt[64 * 72];   // gemm: W^T    [n][k]
    __shared__ int   hist[NBKT];    // scatter
    __shared__ int   cur[NBKT];     // scatter (global write index per bucket)

    const int tid = threadIdx.x;
    const int b   = blockIdx.x;

    if (b % 5 != 4) {
        // ---------------- GEMM tile ----------------
        const int tile = (b / 5) * 4 + (b % 5);
        const int row0 = tile * 64;
        {
            const float4* W4 = (const float4*)W;
            #pragma unroll
            for (int it = 0; it < 4; ++it) {
                int idx = tid + 256 * it;
                int k = idx >> 4, n4 = idx & 15;
                float4 w = W4[idx];
                wt[(n4 * 4 + 0) * 72 + k] = f2bf(w.x);
                wt[(n4 * 4 + 1) * 72 + k] = f2bf(w.y);
                wt[(n4 * 4 + 2) * 72 + k] = f2bf(w.z);
                wt[(n4 * 4 + 3) * 72 + k] = f2bf(w.w);
            }
        }
        {
            const float4* X4 = (const float4*)X + (size_t)row0 * 16;
            #pragma unroll
            for (int it = 0; it < 4; ++it) {
                int idx = tid + 256 * it;
                int r = idx >> 4, c4 = idx & 15;
                float4 v = X4[idx];
                short4 s = { (short)f2bf(v.x), (short)f2bf(v.y),
                             (short)f2bf(v.z), (short)f2bf(v.w) };
                *(short4*)&xs[r * 72 + c4 * 4] = s;
            }
        }
        __syncthreads();

        const int w    = tid >> 6;
        const int lane = tid & 63;
        const int m    = lane & 15;
        const int q    = lane >> 4;

        const int a_off = (16 * w + m) * 72 + q * 8;
        const bf16x8 A0 = *(const bf16x8*)&xs[a_off];
        const bf16x8 A1 = *(const bf16x8*)&xs[a_off + 32];

        floatx4 acc[4];
        #pragma unroll
        for (int t = 0; t < 4; ++t) {
            const int b_off = (16 * t + m) * 72 + q * 8;
            const bf16x8 B0 = *(const bf16x8*)&wt[b_off];
            const bf16x8 B1 = *(const bf16x8*)&wt[b_off + 32];
            floatx4 c = {0.f, 0.f, 0.f, 0.f};
            c = __builtin_amdgcn_mfma_f32_16x16x32_bf16(A0, B0, c, 0, 0, 0);
            c = __builtin_amdgcn_mfma_f32_16x16x32_bf16(A1, B1, c, 0, 0, 0);
            acc[t] = c;
        }
        #pragma unroll
        for (int t = 0; t < 4; ++t)
            #pragma unroll
            for (int r = 0; r < 4; ++r)
                S16[(size_t)(row0 + 16 * w + q * 4 + r) * NF + 16 * t + m] =
                    f2bf(acc[t][r]);
    } else {
        // ---------------- scatter chunk ----------------
        const int chunk = b / 5;
        for (int i = tid; i < NBKT; i += 256) hist[i] = 0;
        __syncthreads();
        const int base = chunk * CHUNK;
        const int lim  = min(CHUNK, n_edges - base);

        if (lim == CHUNK) {
            const int4*   R4 = (const int4*)(rows + base);
            const int4*   C4 = (const int4*)(cols + base);
            const float4* V4 = (const float4*)(vals + base);
            int4 r0 = R4[tid], r1 = R4[tid + 256];
            int4 r2 = R4[tid + 512], r3 = R4[tid + 768];
            #define HINC(rr) atomicAdd(&hist[((unsigned)(rr)) >> shift], 1)
            HINC(r0.x); HINC(r0.y); HINC(r0.z); HINC(r0.w);
            HINC(r1.x); HINC(r1.y); HINC(r1.z); HINC(r1.w);
            HINC(r2.x); HINC(r2.y); HINC(r2.z); HINC(r2.w);
            HINC(r3.x); HINC(r3.y); HINC(r3.z); HINC(r3.w);
            #undef HINC
            __syncthreads();
            for (int i = tid; i < NBKT; i += 256) {
                int h = hist[i];
                cur[i] = h ? (i * BCAP + atomicAdd(&bucket_cursor[i], h)) : 0;
            }
            __syncthreads();
            int4 c0 = C4[tid], c1 = C4[tid + 256];
            int4 c2 = C4[tid + 512], c3 = C4[tid + 768];
            float4 v0 = V4[tid], v1 = V4[tid + 256];
            float4 v2 = V4[tid + 512], v3 = V4[tid + 768];
            #define PUT(rr, cc, vv) { \
                int bkt = ((unsigned)(rr)) >> shift; \
                int p = atomicAdd(&cur[bkt], 1); \
                if (p - bkt * BCAP < BCAP) \
                    staged[p] = make_int2((int)(((unsigned)(rr) << 16) | (unsigned)(cc)), \
                                          __float_as_int(vv)); }
            PUT(r0.x, c0.x, v0.x); PUT(r0.y, c0.y, v0.y);
            PUT(r0.z, c0.z, v0.z); PUT(r0.w, c0.w, v0.w);
            PUT(r1.x, c1.x, v1.x); PUT(r1.y, c1.y, v1.y);
            PUT(r1.z, c1.z, v1.z); PUT(r1.w, c1.w, v1.w);
            PUT(r2.x, c2.x, v2.x); PUT(r2.y, c2.y, v2.y);
            PUT(r2.z, c2.z, v2.z); PUT(r2.w, c2.w, v2.w);
            PUT(r3.x, c3.x, v3.x); PUT(r3.y, c3.y, v3.y);
            PUT(r3.z, c3.z, v3.z); PUT(r3.w, c3.w, v3.w);
            #undef PUT
        } else {
            for (int i = tid; i < lim; i += 256)
                atomicAdd(&hist[((unsigned)rows[base + i]) >> shift], 1);
            __syncthreads();
            for (int i = tid; i < NBKT; i += 256) {
                int h = hist[i];
                cur[i] = h ? (i * BCAP + atomicAdd(&bucket_cursor[i], h)) : 0;
            }
            __syncthreads();
            for (int i = tid; i < lim; i += 256) {
                int r = rows[base + i];
                int bkt = ((unsigned)r) >> shift;
                int p = atomicAdd(&cur[bkt], 1);
                if (p - bkt * BCAP < BCAP)
                    staged[p] = make_int2((int)(((unsigned)r << 16) | (unsigned)cols[base + i]),
                                          __float_as_int(vals[base + i]));
            }
        }
    }
}

// ---------------------------------------------------------------------------
// Kernel 2: NO-SORT bucket accumulate, INT32 fixed-point (scale 2^14).
// One block (1024 thr, 16 waves) per bucket; 32KB LDS int acc[128][64].
// Edges consumed unsorted via wave-uniform loads (scalar pipe); per edge:
// 1 ushort VMEM (S row, lane=feature, 128B/wave) + mul/rndne/cvt + native
// ds_add_u32 (lane=feature -> consecutive addrs, conflict-free, no return).
// No hist, no scan, no sort, no CAS; 2 barriers total.
// ---------------------------------------------------------------------------
__global__ __launch_bounds__(1024) void bucket_accum(
    const int* __restrict__ bucket_cursor, const int2* __restrict__ staged,
    const unsigned short* __restrict__ S16, const float* __restrict__ bias,
    float* __restrict__ out)
{
    __shared__ int acc[RPB * NF];    // 32 KB

    const int k    = blockIdx.x;
    const int t    = threadIdx.x;
    const int w    = t >> 6;
    const int lane = t & 63;

    // zero accumulator: 8192 ints / 1024 thr = 8 each (2x int4)
    {
        int4 z = {0, 0, 0, 0};
        *(int4*)&acc[t * 4] = z;
        *(int4*)&acc[4096 + t * 4] = z;
    }

    const int cnt = min(bucket_cursor[k], BCAP);
    const int2* ep = staged + (size_t)k * BCAP;

    // even split of edges across the 16 waves (rows are NOT partitioned)
    const int per = (cnt + 15) >> 4;
    const int jb  = w * per;
    const int je  = min(jb + per, cnt);

    __syncthreads();

    #define ACC(e) { \
        const unsigned rx = (unsigned)(e).x; \
        const float sv = bf2f(S16[((rx & 0xFFFFu) << 6) + (unsigned)lane]); \
        const float mg = __int_as_float((e).y) * sv; \
        atomicAdd(&acc[(((rx >> 16) & (RPB - 1)) << 6) + lane], \
                  __float2int_rn(mg * SCALE_F)); }

    int j = jb;
    for (; j + 8 <= je; j += 8) {
        const int2 e0 = ep[j + 0];
        const int2 e1 = ep[j + 1];
        const int2 e2 = ep[j + 2];
        const int2 e3 = ep[j + 3];
        const int2 e4 = ep[j + 4];
        const int2 e5 = ep[j + 5];
        const int2 e6 = ep[j + 6];
        const int2 e7 = ep[j + 7];
        ACC(e0); ACC(e1); ACC(e2); ACC(e3);
        ACC(e4); ACC(e5); ACC(e6); ACC(e7);
    }
    for (; j < je; ++j) {
        const int2 e = ep[j];
        ACC(e);
    }
    #undef ACC

    __syncthreads();

    // epilogue: wave w writes rows 8w..8w+7; lane = feature (coalesced)
    const float bv = bias[lane];
    #pragma unroll
    for (int rr = 0; rr < 8; ++rr) {
        const int row = w * 8 + rr;
        const float v = (float)acc[(row << 6) + lane] * INV_SCALE + bv;
        out[((size_t)(k * RPB + row) << 6) + lane] = fmaxf(v, 0.f);
    }
}

extern "C" void kernel_launch(void* const* d_in, const int* in_sizes, int n_in,
                              void* d_out, int out_size, void* d_ws, size_t ws_size,
                              hipStream_t stream)
{
    const float* X     = (const float*)d_in[0];
    const int*   erows = (const int*)  d_in[1];
    const int*   ecols = (const int*)  d_in[2];
    const float* evals = (const float*)d_in[3];
    const float* W     = (const float*)d_in[4];
    const float* bias  = (const float*)d_in[5];
    float*       out   = (float*)d_out;

    const int n_nodes = in_sizes[0] / NF;   // 65536
    const int n_edges = in_sizes[1];        // 1048576
    int shift = 0; while ((NBKT << shift) < n_nodes) ++shift;   // 7

    // workspace layout
    char* ws = (char*)d_ws;
    unsigned short* S16 = (unsigned short*)(ws);                          // 8 MB
    int2* staged        = (int2*)(ws + (size_t)n_nodes * NF * 2);         // 12.6 MB
    int*  bucket_cursor = (int*)((char*)staged + (size_t)NBKT * BCAP * 8);// 2 KB

    const int gemm_tiles = n_nodes / 64;                 // 1024
    const int schunks    = (n_edges + CHUNK - 1) / CHUNK;// 256
    const int mega       = gemm_tiles + schunks;         // 1280 (4:1 interleave)

    hipMemsetAsync(bucket_cursor, 0, (size_t)NBKT * 4, stream);
    gemm_scatter<<<mega, 256, 0, stream>>>(X, W, S16, erows, ecols, evals,
                                           bucket_cursor, staged, n_edges, shift);
    bucket_accum<<<NBKT, 1024, 0, stream>>>(bucket_cursor, staged, S16, bias, out);
}

// Round 4
// 80.534 us; speedup vs baseline: 4.6819x; 1.0271x over previous
//
#include <hip/hip_runtime.h>

// GCN layer: support = X@W ; out = relu(scatter(vals * support[cols]) + bias)
// N_NODES=65536, N_EDGES=1048576, IN_F=OUT_F=64, fp32 in/out.
//
// Ledger: R2 CSR -> R5 bucket sort -> R7 MFMA bf16 GEMM (152) -> R8 fused CSR
// build (144) -> R11 concurrent gemm+scatter mega (143) -> R12 fixed-capacity
// 512-bucket staging + reg-cached LDS sort (52.3) -> R13 per-row global-atomic
// scatter FAILED (120.3) -> R14 LDS float atomicAdd FAILED (377: CAS loop,
// not ds_add_f32) -> R15 int32 fixed-point ds_add_u32 (82.7; accum 57us but
// VGPR=16, all pipes <35% = latency-serialized: per-8-edge dependent chain
// edge-load -> gather, ~2 gathers in flight).
// R16: kill the per-edge dependent round trip. Per 128-edge chunk: each lane
//      bulk-loads 2 edges (int4, 1KB/wave, ONE dwordx4 + one wait); edges
//      distributed via v_readlane (SGPR) -> address math on the SCALAR pipe;
//      gather becomes saddr-form global_load_ushort (uniform base + lane*2),
//      1 VGPR per in-flight gather -> unroll 4 = 8 independent gathers/wave.
//      Per edge: 2 readlane + mul + cvt + ds_add_u32. No sort, no CAS.

#define NF    64
#define NBKT  512      // dst-row buckets; 128 rows each (shift=7)
#define RPB   128      // rows per bucket
#define BCAP  3072     // fixed slots per bucket (mean 2048, +22 sigma)
#define CHUNK 4096     // edges per scatter chunk (256 thr x 16)

#define SCALE_F   16384.0f          // 2^14 fixed-point scale
#define INV_SCALE 6.103515625e-05f  // 2^-14

typedef __attribute__((ext_vector_type(8))) short bf16x8;
typedef __attribute__((ext_vector_type(4))) float floatx4;

__device__ __forceinline__ unsigned short f2bf(float f) {
    unsigned u = __float_as_uint(f);
    return (unsigned short)((u + 0x7FFFu + ((u >> 16) & 1u)) >> 16);   // RNE
}
__device__ __forceinline__ float bf2f(unsigned short h) {
    return __uint_as_float(((unsigned)h) << 16);
}

// ---------------------------------------------------------------------------
// Kernel 1 (MEGA): GEMM tiles and scatter chunks co-resident in one grid.
// 1280 blocks x 256 thr: b%5==4 -> scatter chunk b/5 (256 chunks x 4096
// edges); else gemm tile (b/5)*4+(b%5) (1024 tiles). Scatter writes into
// FIXED bucket regions staged[bkt*BCAP ...] via global cursor reservation
// (one atomic per bucket per chunk, LDS-aggregated); contiguous 64B runs.
// [R12-proven version, unchanged]
// ---------------------------------------------------------------------------
__global__ __launch_bounds__(256) void gemm_scatter(
    const float* __restrict__ X, const float* __restrict__ W,
    unsigned short* __restrict__ S16,
    const int* __restrict__ rows, const int* __restrict__ cols,
    const float* __restrict__ vals, int* __restrict__ bucket_cursor,
    int2* __restrict__ staged, int n_edges, int shift)
{
    __shared__ short xs[64 * 72];   // gemm: X tile [row][k] (2-way alias: free)
    __shared__ short wt[64 * 72];   // gemm: W^T    [n][k]
    __shared__ int   hist[NBKT];    // scatter
    __shared__ int   cur[NBKT];     // scatter (global write index per bucket)

    const int tid = threadIdx.x;
    const int b   = blockIdx.x;

    if (b % 5 != 4) {
        // ---------------- GEMM tile ----------------
        const int tile = (b / 5) * 4 + (b % 5);
        const int row0 = tile * 64;
        {
            const float4* W4 = (const float4*)W;
            #pragma unroll
            for (int it = 0; it < 4; ++it) {
                int idx = tid + 256 * it;
                int k = idx >> 4, n4 = idx & 15;
                float4 w = W4[idx];
                wt[(n4 * 4 + 0) * 72 + k] = f2bf(w.x);
                wt[(n4 * 4 + 1) * 72 + k] = f2bf(w.y);
                wt[(n4 * 4 + 2) * 72 + k] = f2bf(w.z);
                wt[(n4 * 4 + 3) * 72 + k] = f2bf(w.w);
            }
        }
        {
            const float4* X4 = (const float4*)X + (size_t)row0 * 16;
            #pragma unroll
            for (int it = 0; it < 4; ++it) {
                int idx = tid + 256 * it;
                int r = idx >> 4, c4 = idx & 15;
                float4 v = X4[idx];
                short4 s = { (short)f2bf(v.x), (short)f2bf(v.y),
                             (short)f2bf(v.z), (short)f2bf(v.w) };
                *(short4*)&xs[r * 72 + c4 * 4] = s;
            }
        }
        __syncthreads();

        const int w    = tid >> 6;
        const int lane = tid & 63;
        const int m    = lane & 15;
        const int q    = lane >> 4;

        const int a_off = (16 * w + m) * 72 + q * 8;
        const bf16x8 A0 = *(const bf16x8*)&xs[a_off];
        const bf16x8 A1 = *(const bf16x8*)&xs[a_off + 32];

        floatx4 acc[4];
        #pragma unroll
        for (int t = 0; t < 4; ++t) {
            const int b_off = (16 * t + m) * 72 + q * 8;
            const bf16x8 B0 = *(const bf16x8*)&wt[b_off];
            const bf16x8 B1 = *(const bf16x8*)&wt[b_off + 32];
            floatx4 c = {0.f, 0.f, 0.f, 0.f};
            c = __builtin_amdgcn_mfma_f32_16x16x32_bf16(A0, B0, c, 0, 0, 0);
            c = __builtin_amdgcn_mfma_f32_16x16x32_bf16(A1, B1, c, 0, 0, 0);
            acc[t] = c;
        }
        #pragma unroll
        for (int t = 0; t < 4; ++t)
            #pragma unroll
            for (int r = 0; r < 4; ++r)
                S16[(size_t)(row0 + 16 * w + q * 4 + r) * NF + 16 * t + m] =
                    f2bf(acc[t][r]);
    } else {
        // ---------------- scatter chunk ----------------
        const int chunk = b / 5;
        for (int i = tid; i < NBKT; i += 256) hist[i] = 0;
        __syncthreads();
        const int base = chunk * CHUNK;
        const int lim  = min(CHUNK, n_edges - base);

        if (lim == CHUNK) {
            const int4*   R4 = (const int4*)(rows + base);
            const int4*   C4 = (const int4*)(cols + base);
            const float4* V4 = (const float4*)(vals + base);
            int4 r0 = R4[tid], r1 = R4[tid + 256];
            int4 r2 = R4[tid + 512], r3 = R4[tid + 768];
            #define HINC(rr) atomicAdd(&hist[((unsigned)(rr)) >> shift], 1)
            HINC(r0.x); HINC(r0.y); HINC(r0.z); HINC(r0.w);
            HINC(r1.x); HINC(r1.y); HINC(r1.z); HINC(r1.w);
            HINC(r2.x); HINC(r2.y); HINC(r2.z); HINC(r2.w);
            HINC(r3.x); HINC(r3.y); HINC(r3.z); HINC(r3.w);
            #undef HINC
            __syncthreads();
            for (int i = tid; i < NBKT; i += 256) {
                int h = hist[i];
                cur[i] = h ? (i * BCAP + atomicAdd(&bucket_cursor[i], h)) : 0;
            }
            __syncthreads();
            int4 c0 = C4[tid], c1 = C4[tid + 256];
            int4 c2 = C4[tid + 512], c3 = C4[tid + 768];
            float4 v0 = V4[tid], v1 = V4[tid + 256];
            float4 v2 = V4[tid + 512], v3 = V4[tid + 768];
            #define PUT(rr, cc, vv) { \
                int bkt = ((unsigned)(rr)) >> shift; \
                int p = atomicAdd(&cur[bkt], 1); \
                if (p - bkt * BCAP < BCAP) \
                    staged[p] = make_int2((int)(((unsigned)(rr) << 16) | (unsigned)(cc)), \
                                          __float_as_int(vv)); }
            PUT(r0.x, c0.x, v0.x); PUT(r0.y, c0.y, v0.y);
            PUT(r0.z, c0.z, v0.z); PUT(r0.w, c0.w, v0.w);
            PUT(r1.x, c1.x, v1.x); PUT(r1.y, c1.y, v1.y);
            PUT(r1.z, c1.z, v1.z); PUT(r1.w, c1.w, v1.w);
            PUT(r2.x, c2.x, v2.x); PUT(r2.y, c2.y, v2.y);
            PUT(r2.z, c2.z, v2.z); PUT(r2.w, c2.w, v2.w);
            PUT(r3.x, c3.x, v3.x); PUT(r3.y, c3.y, v3.y);
            PUT(r3.z, c3.z, v3.z); PUT(r3.w, c3.w, v3.w);
            #undef PUT
        } else {
            for (int i = tid; i < lim; i += 256)
                atomicAdd(&hist[((unsigned)rows[base + i]) >> shift], 1);
            __syncthreads();
            for (int i = tid; i < NBKT; i += 256) {
                int h = hist[i];
                cur[i] = h ? (i * BCAP + atomicAdd(&bucket_cursor[i], h)) : 0;
            }
            __syncthreads();
            for (int i = tid; i < lim; i += 256) {
                int r = rows[base + i];
                int bkt = ((unsigned)r) >> shift;
                int p = atomicAdd(&cur[bkt], 1);
                if (p - bkt * BCAP < BCAP)
                    staged[p] = make_int2((int)(((unsigned)r << 16) | (unsigned)cols[base + i]),
                                          __float_as_int(vals[base + i]));
            }
        }
    }
}

// ---------------------------------------------------------------------------
// Kernel 2: NO-SORT bucket accumulate, INT32 fixed-point (scale 2^14).
// One block (1024 thr, 16 waves) per bucket; 32KB LDS int acc[128][64].
// Per 128-edge chunk: lane l bulk-loads edges (c+2l, c+2l+1) as one int4;
// edges distributed via v_readlane -> row/col/val are SGPRs, address math on
// the scalar pipe; gather is saddr-form global_load_ushort (uniform base +
// lane*2). Per edge: 2 readlane + v_mul + cvt + native ds_add_u32
// (lane=feature, conflict-free, no return). No sort, no CAS; 2 barriers.
// ---------------------------------------------------------------------------
__global__ __launch_bounds__(1024) void bucket_accum(
    const int* __restrict__ bucket_cursor, const int2* __restrict__ staged,
    const unsigned short* __restrict__ S16, const float* __restrict__ bias,
    float* __restrict__ out)
{
    __shared__ int acc[RPB * NF];    // 32 KB

    const int k    = blockIdx.x;
    const int t    = threadIdx.x;
    const int w    = t >> 6;
    const int lane = t & 63;

    // zero accumulator: 8192 ints / 1024 thr = 8 each (2x int4)
    {
        int4 z = {0, 0, 0, 0};
        *(int4*)&acc[t * 4] = z;
        *(int4*)&acc[4096 + t * 4] = z;
    }

    const int cnt = min(bucket_cursor[k], BCAP);
    const int2* ep = staged + (size_t)k * BCAP;

    // even split of edges across the 16 waves; per forced EVEN so that the
    // per-lane int4 bulk loads stay 16B-aligned.
    const int per = (((cnt + 15) >> 4) + 1) & ~1;
    const int jb  = w * per;
    const int je  = min(jb + per, cnt);

    __syncthreads();

    // process one edge whose payload lives in SGPRs (rx = row<<16|col, vy = val bits)
    #define ACCS(rx, vy) { \
        const unsigned short* sp_ = S16 + ((((unsigned)(rx)) & 0xFFFFu) << 6); \
        const float sv_ = bf2f(sp_[lane]); \
        const float mg_ = __int_as_float(vy) * sv_; \
        atomicAdd(&acc[(((((unsigned)(rx)) >> 16) & (RPB - 1)) << 6) + lane], \
                  __float2int_rn(mg_ * SCALE_F)); }

    for (int c = jb; c < je; c += 128) {
        // bulk edge load: lane l holds edges (c+2l, c+2l+1) in one int4
        int4 ed = {0, 0, 0, 0};
        {
            const int myj = c + 2 * lane;
            if (myj + 1 < je) {
                ed = *(const int4*)(ep + myj);          // 16B, aligned (c even)
            } else if (myj < je) {
                const int2 e = ep[myj];
                ed.x = e.x; ed.y = e.y;
            }
        }
        const int n = min(128, je - c);

        int i = 0;
        #pragma unroll 4
        for (; i + 2 <= n; i += 2) {
            const int sl  = i >> 1;
            const int ax  = __builtin_amdgcn_readlane(ed.x, sl);
            const int ay  = __builtin_amdgcn_readlane(ed.y, sl);
            ACCS(ax, ay);
            const int bx  = __builtin_amdgcn_readlane(ed.z, sl);
            const int by  = __builtin_amdgcn_readlane(ed.w, sl);
            ACCS(bx, by);
        }
        if (i < n) {                                    // odd tail (even index)
            const int sl = i >> 1;
            const int ax = __builtin_amdgcn_readlane(ed.x, sl);
            const int ay = __builtin_amdgcn_readlane(ed.y, sl);
            ACCS(ax, ay);
        }
    }
    #undef ACCS

    __syncthreads();

    // epilogue: wave w writes rows 8w..8w+7; lane = feature (coalesced)
    const float bv = bias[lane];
    #pragma unroll
    for (int rr = 0; rr < 8; ++rr) {
        const int row = w * 8 + rr;
        const float v = (float)acc[(row << 6) + lane] * INV_SCALE + bv;
        out[((size_t)(k * RPB + row) << 6) + lane] = fmaxf(v, 0.f);
    }
}

extern "C" void kernel_launch(void* const* d_in, const int* in_sizes, int n_in,
                              void* d_out, int out_size, void* d_ws, size_t ws_size,
                              hipStream_t stream)
{
    const float* X     = (const float*)d_in[0];
    const int*   erows = (const int*)  d_in[1];
    const int*   ecols = (const int*)  d_in[2];
    const float* evals = (const float*)d_in[3];
    const float* W     = (const float*)d_in[4];
    const float* bias  = (const float*)d_in[5];
    float*       out   = (float*)d_out;

    const int n_nodes = in_sizes[0] / NF;   // 65536
    const int n_edges = in_sizes[1];        // 1048576
    int shift = 0; while ((NBKT << shift) < n_nodes) ++shift;   // 7

    // workspace layout
    char* ws = (char*)d_ws;
    unsigned short* S16 = (unsigned short*)(ws);                          // 8 MB
    int2* staged        = (int2*)(ws + (size_t)n_nodes * NF * 2);         // 12.6 MB
    int*  bucket_cursor = (int*)((char*)staged + (size_t)NBKT * BCAP * 8);// 2 KB

    const int gemm_tiles = n_nodes / 64;                 // 1024
    const int schunks    = (n_edges + CHUNK - 1) / CHUNK;// 256
    const int mega       = gemm_tiles + schunks;         // 1280 (4:1 interleave)

    hipMemsetAsync(bucket_cursor, 0, (size_t)NBKT * 4, stream);
    gemm_scatter<<<mega, 256, 0, stream>>>(X, W, S16, erows, ecols, evals,
                                           bucket_cursor, staged, n_edges, shift);
    bucket_accum<<<NBKT, 1024, 0, stream>>>(bucket_cursor, staged, S16, bias, out);
}

// Round 5
// 51.636 us; speedup vs baseline: 7.3021x; 1.5597x over previous
//
#include <hip/hip_runtime.h>

// GCN layer: support = X@W ; out = relu(scatter(vals * support[cols]) + bias)
// N_NODES=65536, N_EDGES=1048576, IN_F=OUT_F=64, fp32 in/out.
//
// Ledger: R2 CSR -> R5 bucket sort -> R7 MFMA bf16 GEMM (152) -> R8 fused CSR
// build (144) -> R11 concurrent gemm+scatter mega (143) -> R12 fixed-capacity
// 512-bucket staging + reg-cached LDS sort (52.3) -> R13 per-row global-atomic
// scatter FAILED (120.3) -> R14 LDS float atomicAdd FAILED (377: CAS loop) ->
// R15 int32 ds_add_u32 (82.7) -> R16 readlane/saddr restructure NEUTRAL (80.5).
// LESSON (R14-R16): hipcc does NOT pipeline loops containing LDS atomics
// (VGPR pinned at 16, 1 gather in flight, ~1000 cy/edge). Register
// accumulation over sorted runs (R12 phase B) is the only structure that
// pipelines. R17: revert to R12 + pack 2 edges/instr in phase B:
//   half-wave h owns edge stream j+h; lane covers features 2fl,2fl+1.
//   1 ds_read_b64 = 2 edges (2-addr broadcast, free); 1 global_load_dword
//   = 2 edges' S-rows (VMEM instrs halved, sectors same); 4 loads in
//   flight cover 8 edges. Row end: 2x shfl_xor(32) merge + float2 store.

#define NF    64
#define NBKT  512      // dst-row buckets; 128 rows each (shift=7)
#define RPB   128      // rows per bucket
#define BCAP  3072     // fixed slots per bucket (mean 2048, +22 sigma)
#define CHUNK 4096     // edges per scatter chunk (256 thr x 16)

typedef __attribute__((ext_vector_type(8))) short bf16x8;
typedef __attribute__((ext_vector_type(4))) float floatx4;

__device__ __forceinline__ unsigned short f2bf(float f) {
    unsigned u = __float_as_uint(f);
    return (unsigned short)((u + 0x7FFFu + ((u >> 16) & 1u)) >> 16);   // RNE
}
__device__ __forceinline__ float bf2f(unsigned short h) {
    return __uint_as_float(((unsigned)h) << 16);
}

// ---------------------------------------------------------------------------
// Kernel 1 (MEGA): GEMM tiles and scatter chunks co-resident in one grid.
// 1280 blocks x 256 thr: b%5==4 -> scatter chunk b/5 (256 chunks x 4096
// edges); else gemm tile (b/5)*4+(b%5) (1024 tiles). Scatter writes into
// FIXED bucket regions staged[bkt*BCAP ...] via global cursor reservation
// (one atomic per bucket per chunk, LDS-aggregated); contiguous 64B runs.
// [R12-proven version, unchanged]
// ---------------------------------------------------------------------------
__global__ __launch_bounds__(256) void gemm_scatter(
    const float* __restrict__ X, const float* __restrict__ W,
    unsigned short* __restrict__ S16,
    const int* __restrict__ rows, const int* __restrict__ cols,
    const float* __restrict__ vals, int* __restrict__ bucket_cursor,
    int2* __restrict__ staged, int n_edges, int shift)
{
    __shared__ short xs[64 * 72];   // gemm: X tile [row][k] (2-way alias: free)
    __shared__ short wt[64 * 72];   // gemm: W^T    [n][k]
    __shared__ int   hist[NBKT];    // scatter
    __shared__ int   cur[NBKT];     // scatter (global write index per bucket)

    const int tid = threadIdx.x;
    const int b   = blockIdx.x;

    if (b % 5 != 4) {
        // ---------------- GEMM tile ----------------
        const int tile = (b / 5) * 4 + (b % 5);
        const int row0 = tile * 64;
        {
            const float4* W4 = (const float4*)W;
            #pragma unroll
            for (int it = 0; it < 4; ++it) {
                int idx = tid + 256 * it;
                int k = idx >> 4, n4 = idx & 15;
                float4 w = W4[idx];
                wt[(n4 * 4 + 0) * 72 + k] = f2bf(w.x);
                wt[(n4 * 4 + 1) * 72 + k] = f2bf(w.y);
                wt[(n4 * 4 + 2) * 72 + k] = f2bf(w.z);
                wt[(n4 * 4 + 3) * 72 + k] = f2bf(w.w);
            }
        }
        {
            const float4* X4 = (const float4*)X + (size_t)row0 * 16;
            #pragma unroll
            for (int it = 0; it < 4; ++it) {
                int idx = tid + 256 * it;
                int r = idx >> 4, c4 = idx & 15;
                float4 v = X4[idx];
                short4 s = { (short)f2bf(v.x), (short)f2bf(v.y),
                             (short)f2bf(v.z), (short)f2bf(v.w) };
                *(short4*)&xs[r * 72 + c4 * 4] = s;
            }
        }
        __syncthreads();

        const int w    = tid >> 6;
        const int lane = tid & 63;
        const int m    = lane & 15;
        const int q    = lane >> 4;

        const int a_off = (16 * w + m) * 72 + q * 8;
        const bf16x8 A0 = *(const bf16x8*)&xs[a_off];
        const bf16x8 A1 = *(const bf16x8*)&xs[a_off + 32];

        floatx4 acc[4];
        #pragma unroll
        for (int t = 0; t < 4; ++t) {
            const int b_off = (16 * t + m) * 72 + q * 8;
            const bf16x8 B0 = *(const bf16x8*)&wt[b_off];
            const bf16x8 B1 = *(const bf16x8*)&wt[b_off + 32];
            floatx4 c = {0.f, 0.f, 0.f, 0.f};
            c = __builtin_amdgcn_mfma_f32_16x16x32_bf16(A0, B0, c, 0, 0, 0);
            c = __builtin_amdgcn_mfma_f32_16x16x32_bf16(A1, B1, c, 0, 0, 0);
            acc[t] = c;
        }
        #pragma unroll
        for (int t = 0; t < 4; ++t)
            #pragma unroll
            for (int r = 0; r < 4; ++r)
                S16[(size_t)(row0 + 16 * w + q * 4 + r) * NF + 16 * t + m] =
                    f2bf(acc[t][r]);
    } else {
        // ---------------- scatter chunk ----------------
        const int chunk = b / 5;
        for (int i = tid; i < NBKT; i += 256) hist[i] = 0;
        __syncthreads();
        const int base = chunk * CHUNK;
        const int lim  = min(CHUNK, n_edges - base);

        if (lim == CHUNK) {
            const int4*   R4 = (const int4*)(rows + base);
            const int4*   C4 = (const int4*)(cols + base);
            const float4* V4 = (const float4*)(vals + base);
            int4 r0 = R4[tid], r1 = R4[tid + 256];
            int4 r2 = R4[tid + 512], r3 = R4[tid + 768];
            #define HINC(rr) atomicAdd(&hist[((unsigned)(rr)) >> shift], 1)
            HINC(r0.x); HINC(r0.y); HINC(r0.z); HINC(r0.w);
            HINC(r1.x); HINC(r1.y); HINC(r1.z); HINC(r1.w);
            HINC(r2.x); HINC(r2.y); HINC(r2.z); HINC(r2.w);
            HINC(r3.x); HINC(r3.y); HINC(r3.z); HINC(r3.w);
            #undef HINC
            __syncthreads();
            for (int i = tid; i < NBKT; i += 256) {
                int h = hist[i];
                cur[i] = h ? (i * BCAP + atomicAdd(&bucket_cursor[i], h)) : 0;
            }
            __syncthreads();
            int4 c0 = C4[tid], c1 = C4[tid + 256];
            int4 c2 = C4[tid + 512], c3 = C4[tid + 768];
            float4 v0 = V4[tid], v1 = V4[tid + 256];
            float4 v2 = V4[tid + 512], v3 = V4[tid + 768];
            #define PUT(rr, cc, vv) { \
                int bkt = ((unsigned)(rr)) >> shift; \
                int p = atomicAdd(&cur[bkt], 1); \
                if (p - bkt * BCAP < BCAP) \
                    staged[p] = make_int2((int)(((unsigned)(rr) << 16) | (unsigned)(cc)), \
                                          __float_as_int(vv)); }
            PUT(r0.x, c0.x, v0.x); PUT(r0.y, c0.y, v0.y);
            PUT(r0.z, c0.z, v0.z); PUT(r0.w, c0.w, v0.w);
            PUT(r1.x, c1.x, v1.x); PUT(r1.y, c1.y, v1.y);
            PUT(r1.z, c1.z, v1.z); PUT(r1.w, c1.w, v1.w);
            PUT(r2.x, c2.x, v2.x); PUT(r2.y, c2.y, v2.y);
            PUT(r2.z, c2.z, v2.z); PUT(r2.w, c2.w, v2.w);
            PUT(r3.x, c3.x, v3.x); PUT(r3.y, c3.y, v3.y);
            PUT(r3.z, c3.z, v3.z); PUT(r3.w, c3.w, v3.w);
            #undef PUT
        } else {
            for (int i = tid; i < lim; i += 256)
                atomicAdd(&hist[((unsigned)rows[base + i]) >> shift], 1);
            __syncthreads();
            for (int i = tid; i < NBKT; i += 256) {
                int h = hist[i];
                cur[i] = h ? (i * BCAP + atomicAdd(&bucket_cursor[i], h)) : 0;
            }
            __syncthreads();
            for (int i = tid; i < lim; i += 256) {
                int r = rows[base + i];
                int bkt = ((unsigned)r) >> shift;
                int p = atomicAdd(&cur[bkt], 1);
                if (p - bkt * BCAP < BCAP)
                    staged[p] = make_int2((int)(((unsigned)r << 16) | (unsigned)cols[base + i]),
                                          __float_as_int(vals[base + i]));
            }
        }
    }
}

// ---------------------------------------------------------------------------
// Kernel 2: one block (1024 thr, 16 waves) per bucket.
// Phase A [R12-proven]: edges reg-cached (3/thread) -> LDS hist -> scan ->
// LDS-cursor sort into eds, storing (col<<6, val).
// Phase B [NEW]: wave w owns rows 8w..8w+7. Lane = (h, fl): half-wave h
// runs edge stream j+h for the row; fl covers features 2fl,2fl+1.
// Per 2 edges: 1 ds_read_b64 (2-addr broadcast) + 1 global_load_dword
// (2 S-rows, sectors unchanged) + 4 fmacs. Row end: shfl_xor(32) merge,
// half-wave float2 store with fused bias+ReLU.
// ---------------------------------------------------------------------------
__global__ __launch_bounds__(1024) void bucket_gather(
    const int* __restrict__ bucket_cursor, const int2* __restrict__ staged,
    const unsigned short* __restrict__ S16, const float* __restrict__ bias,
    float* __restrict__ out)
{
    __shared__ int2 eds[BCAP];         // 24 KB
    __shared__ int  hist[RPB];
    __shared__ int  cur[RPB];
    __shared__ int  rstart[RPB + 1];

    const int k    = blockIdx.x;
    const int t    = threadIdx.x;
    const int cnt  = min(bucket_cursor[k], BCAP);
    const int base = k * BCAP;
    const int w    = t >> 6;
    const int lane = t & 63;

    // phase A: register-cached edges (3 per thread; 3072 = 3 x 1024)
    int2 eb[3];
    bool vld[3];
    #pragma unroll
    for (int p = 0; p < 3; ++p) {
        const int i = t + 1024 * p;
        vld[p] = (i < cnt);
        if (vld[p]) eb[p] = staged[base + i];
    }
    if (t < RPB) hist[t] = 0;
    __syncthreads();
    #pragma unroll
    for (int p = 0; p < 3; ++p)
        if (vld[p])
            atomicAdd(&hist[(((unsigned)eb[p].x) >> 16) & (RPB - 1)], 1);
    __syncthreads();
    const int v = (t < RPB) ? hist[t] : 0;
    for (int off = 1; off < RPB; off <<= 1) {
        int u = (t < RPB && t >= off) ? hist[t - off] : 0;
        __syncthreads();
        if (t < RPB) hist[t] += u;
        __syncthreads();
    }
    if (t < RPB) {
        rstart[t] = hist[t] - v;       // exclusive, bucket-relative
        cur[t]    = hist[t] - v;
    }
    if (t == 0) rstart[RPB] = cnt;
    __syncthreads();
    #pragma unroll
    for (int p = 0; p < 3; ++p)
        if (vld[p]) {
            int r = (((unsigned)eb[p].x) >> 16) & (RPB - 1);
            int pos = atomicAdd(&cur[r], 1);
            // store ushort-index of the S row (col*64) + value
            eds[pos] = make_int2((eb[p].x & 0xFFFF) << 6, eb[p].y);
        }
    __syncthreads();

    // ---------------- phase B: 2-edge-packed register accumulate ----------
    const int h  = lane >> 5;          // edge-stream half
    const int fl = lane & 31;          // feature pair: features 2fl, 2fl+1
    const float bvx = bias[2 * fl];
    const float bvy = bias[2 * fl + 1];

    #pragma unroll
    for (int rr = 0; rr < 8; ++rr) {
        const int row = w * 8 + rr;
        const int jb = rstart[row];
        const int je = rstart[row + 1];
        float a0 = 0.f, a1 = 0.f, b0 = 0.f, b1 = 0.f;
        float c0 = 0.f, c1 = 0.f, d0 = 0.f, d1 = 0.f;
        int j = jb;
        for (; j + 8 <= je; j += 8) {
            // slot s covers edges j+2s+h
            const int2 e0 = eds[j + 0 + h];
            const int2 e1 = eds[j + 2 + h];
            const int2 e2 = eds[j + 4 + h];
            const int2 e3 = eds[j + 6 + h];
            const unsigned s0 = *(const unsigned*)(S16 + (unsigned)e0.x + 2 * fl);
            const unsigned s1 = *(const unsigned*)(S16 + (unsigned)e1.x + 2 * fl);
            const unsigned s2 = *(const unsigned*)(S16 + (unsigned)e2.x + 2 * fl);
            const unsigned s3 = *(const unsigned*)(S16 + (unsigned)e3.x + 2 * fl);
            const float v0 = __int_as_float(e0.y);
            const float v1 = __int_as_float(e1.y);
            const float v2 = __int_as_float(e2.y);
            const float v3 = __int_as_float(e3.y);
            a0 += v0 * bf2f((unsigned short)s0);
            a1 += v0 * bf2f((unsigned short)(s0 >> 16));
            b0 += v1 * bf2f((unsigned short)s1);
            b1 += v1 * bf2f((unsigned short)(s1 >> 16));
            c0 += v2 * bf2f((unsigned short)s2);
            c1 += v2 * bf2f((unsigned short)(s2 >> 16));
            d0 += v3 * bf2f((unsigned short)s3);
            d1 += v3 * bf2f((unsigned short)(s3 >> 16));
        }
        for (; j < je; j += 2) {
            const int jj  = j + h;
            const bool on = (jj < je);
            const int2 e  = eds[on ? jj : (je - 1)];     // clamp: valid addr
            const unsigned s = *(const unsigned*)(S16 + (unsigned)e.x + 2 * fl);
            const float vv = on ? __int_as_float(e.y) : 0.f;
            a0 += vv * bf2f((unsigned short)s);
            a1 += vv * bf2f((unsigned short)(s >> 16));
        }
        float ae = (a0 + b0) + (c0 + d0);
        float ao = (a1 + b1) + (c1 + d1);
        ae += __shfl_xor(ae, 32);      // merge the two edge streams
        ao += __shfl_xor(ao, 32);
        if (h == 0) {
            float2 o;
            o.x = fmaxf(ae + bvx, 0.f);
            o.y = fmaxf(ao + bvy, 0.f);
            *(float2*)(out + (((size_t)(k * RPB + row)) << 6) + 2 * fl) = o;
        }
    }
}

extern "C" void kernel_launch(void* const* d_in, const int* in_sizes, int n_in,
                              void* d_out, int out_size, void* d_ws, size_t ws_size,
                              hipStream_t stream)
{
    const float* X     = (const float*)d_in[0];
    const int*   erows = (const int*)  d_in[1];
    const int*   ecols = (const int*)  d_in[2];
    const float* evals = (const float*)d_in[3];
    const float* W     = (const float*)d_in[4];
    const float* bias  = (const float*)d_in[5];
    float*       out   = (float*)d_out;

    const int n_nodes = in_sizes[0] / NF;   // 65536
    const int n_edges = in_sizes[1];        // 1048576
    int shift = 0; while ((NBKT << shift) < n_nodes) ++shift;   // 7

    // workspace layout
    char* ws = (char*)d_ws;
    unsigned short* S16 = (unsigned short*)(ws);                          // 8 MB
    int2* staged        = (int2*)(ws + (size_t)n_nodes * NF * 2);         // 12.6 MB
    int*  bucket_cursor = (int*)((char*)staged + (size_t)NBKT * BCAP * 8);// 2 KB

    const int gemm_tiles = n_nodes / 64;                 // 1024
    const int schunks    = (n_edges + CHUNK - 1) / CHUNK;// 256
    const int mega       = gemm_tiles + schunks;         // 1280 (4:1 interleave)

    hipMemsetAsync(bucket_cursor, 0, (size_t)NBKT * 4, stream);
    gemm_scatter<<<mega, 256, 0, stream>>>(X, W, S16, erows, ecols, evals,
                                           bucket_cursor, staged, n_edges, shift);
    bucket_gather<<<NBKT, 1024, 0, stream>>>(bucket_cursor, staged, S16, bias, out);
}